// Round 7
// baseline (219.323 us; speedup 1.0000x reference)
//
#include <hip/hip_runtime.h>

#define NR  8192
#define DIM 512
#define BM  256
#define KS  32           // K-step (elements)
#define NKS 16           // DIM / KS

typedef __attribute__((ext_vector_type(8))) short bf16x8;
typedef __attribute__((ext_vector_type(4))) float f32x4;
typedef unsigned short u16;
typedef unsigned int   u32;

__device__ __forceinline__ void gload16(const void* g, void* l) {
    __builtin_amdgcn_global_load_lds((const __attribute__((address_space(1))) void*)g,
                                     (__attribute__((address_space(3))) void*)l,
                                     16, 0, 0);
}

// ================= fp32 -> bf16 + norms (of bf16-rounded values) =================
__global__ __launch_bounds__(256) void conv_bf16(const float* __restrict__ x,
                                                 const float* __restrict__ y,
                                                 u16* __restrict__ xb, u16* __restrict__ yb,
                                                 float* __restrict__ xn, float* __restrict__ yn) {
    int gw = (blockIdx.x * 256 + threadIdx.x) >> 6;
    int lane = threadIdx.x & 63;
    if (gw >= 2 * NR) return;
    int row = (gw < NR) ? gw : gw - NR;
    const float* src = (gw < NR) ? x : y;
    u16*   dst = (gw < NR) ? xb : yb;
    float* nrm = (gw < NR) ? xn : yn;

    const float4* p = (const float4*)(src + (size_t)row * DIM);
    float4 v0 = p[lane * 2], v1 = p[lane * 2 + 1];
    float vv[8] = {v0.x, v0.y, v0.z, v0.w, v1.x, v1.y, v1.z, v1.w};
    u16 us[8]; float s = 0.f;
    #pragma unroll
    for (int i = 0; i < 8; ++i) {
        u32 u = __float_as_uint(vv[i]);
        u16 b = (u16)((u + 0x7FFFu + ((u >> 16) & 1u)) >> 16);   // RNE fp32->bf16
        us[i] = b;
        float bf = __uint_as_float(((u32)b) << 16);
        s += bf * bf;
    }
    *(bf16x8*)(dst + (size_t)row * DIM + lane * 8) = *(const bf16x8*)us;
    #pragma unroll
    for (int off = 32; off; off >>= 1) s += __shfl_down(s, off, 64);
    if (lane == 0) nrm[row] = s;
}

__global__ void zero_kernel(double* acc) {
    if (threadIdx.x == 0 && blockIdx.x == 0) *acc = 0.0;
}

__global__ void finalize_kernel(const double* __restrict__ acc, float* __restrict__ out) {
    if (threadIdx.x == 0 && blockIdx.x == 0) {
        double n2 = (double)NR * (double)NR;
        out[0] = (float)(*acc / n2);
    }
}

// ================= 256^2-tile, 8-wave, 4-slot-ring phased MFMA kernel =================
// logical grid 2080: [0,528) xx upper-tri, [528,1056) yy upper-tri, [1056,2080) xy (weight -2)
__global__ __launch_bounds__(512, 2) void mmd_bf16(const u16* __restrict__ xb, const u16* __restrict__ yb,
                                                   const float* __restrict__ xn, const float* __restrict__ yn,
                                                   double* __restrict__ acc) {
    int f = (blockIdx.x & 7) * 260 + (blockIdx.x >> 3);   // T1 bijective XCD swizzle
    int z, bi, bj;
    if (f < 1056) {
        z = (f < 528) ? 0 : 1;
        int t = (f < 528) ? f : f - 528;
        int r = (int)((sqrtf(8.f * t + 1.f) - 1.f) * 0.5f);
        while ((r + 1) * (r + 2) / 2 <= t) ++r;
        while (r * (r + 1) / 2 > t) --r;
        bi = t - r * (r + 1) / 2;   // bi <= bj
        bj = r;
    } else {
        z = 2; int t = f - 1056; bi = t >> 5; bj = t & 31;
    }
    const u16*   A  = (z == 1) ? yb : xb;
    const u16*   B  = (z == 0) ? xb : yb;
    const float* an = (z == 1) ? yn : xn;
    const float* bn = (z == 0) ? xn : yn;
    const float wgt = (z == 2) ? -2.f : ((bi == bj) ? 1.f : 2.f);
    const int bm = bi * BM, bnc = bj * BM;

    // 4-slot ring per matrix: slot = kstep & 3, each 256 rows x 32 elems (64 B/row) = 16 KiB
    // total 2 * 4 * 16 KiB = 128 KiB
    __shared__ __align__(16) u16 Al[4][BM * KS];
    __shared__ __align__(16) u16 Bl[4][BM * KS];

    const int tid = threadIdx.x, w = tid >> 6, lane = tid & 63;
    const int wm = w >> 2, wn = w & 3;            // 2x4 wave grid; per-wave 128x64 out
    const int fr = lane & 15, kg = lane >> 4;

    // ---- staging lane mapping: one gload = 16 rows x 64 B; lane -> row lane>>2, slot lane&3
    const int srow  = lane >> 2;                           // 0..15
    const int sslot = (lane & 3) ^ ((lane >> 4) & 3);      // pre-swizzled source 16B slot

    // ---- read-side lane constants (swizzle: phys slot = kg ^ ((row>>2)&3)) ----
    const int sw   = (fr >> 2) & 3;
    const int aoff = (kg ^ sw) * 8;                        // elems within 32-elem row
    int raO[8], rbO[4];
    #pragma unroll
    for (int fm = 0; fm < 8; ++fm) raO[fm] = (wm * 128 + fm * 16 + fr) * KS + aoff;
    #pragma unroll
    for (int fn = 0; fn < 4; ++fn) rbO[fn] = (wn * 64 + fn * 16 + fr) * KS + aoff;

    f32x4 acc4[8][4];
    #pragma unroll
    for (int i = 0; i < 8; ++i)
        #pragma unroll
        for (int j = 0; j < 4; ++j)
            acc4[i][j] = {0.f, 0.f, 0.f, 0.f};

    // staging source bases (u16 units); round q=1 adds 16*DIM
    const size_t aBase = (size_t)(bm  + w * 32 + srow) * DIM + sslot * 8;
    const size_t bBase = (size_t)(bnc + w * 32 + srow) * DIM + sslot * 8;

#define STAGEA(kt, slot)                                                                   \
    {                                                                                      \
        gload16(A + aBase +            (size_t)(kt) * KS, &Al[slot][(w * 32     ) * KS]);  \
        gload16(A + aBase + 16 * DIM + (size_t)(kt) * KS, &Al[slot][(w * 32 + 16) * KS]);  \
    }
#define STAGEB(kt, slot)                                                                   \
    {                                                                                      \
        gload16(B + bBase +            (size_t)(kt) * KS, &Bl[slot][(w * 32     ) * KS]);  \
        gload16(B + bBase + 16 * DIM + (size_t)(kt) * KS, &Bl[slot][(w * 32 + 16) * KS]);  \
    }

    // prologue: stage ksteps 0,1,2 (12 loads); wait oldest 4 (tile 0), 8 in flight
    STAGEA(0, 0) STAGEB(0, 0)
    STAGEA(1, 1) STAGEB(1, 1)
    STAGEA(2, 2) STAGEB(2, 2)
    asm volatile("s_waitcnt vmcnt(8)" ::: "memory");
    __builtin_amdgcn_s_barrier();

    #pragma unroll
    for (int kt = 0; kt < NKS; ++kt) {
        const int cs = kt & 3;
        const int ns = (kt + 3) & 3;         // slot freed at phase kt-1's closing barrier
        const u16* Ab = &Al[cs][0];
        const u16* Bb = &Bl[cs][0];

        // ---------- sub-phase 0: stage A(kt+3) | read af0..3,bf0..3 | 16 MFMA ----------
        if (kt <= NKS - 4) STAGEA(kt + 3, ns)
        bf16x8 bfr[4], af0[4];
        #pragma unroll
        for (int fn = 0; fn < 4; ++fn) bfr[fn] = *(const bf16x8*)(Bb + rbO[fn]);
        #pragma unroll
        for (int fm = 0; fm < 4; ++fm) af0[fm] = *(const bf16x8*)(Ab + raO[fm]);
        __builtin_amdgcn_s_barrier();
        __builtin_amdgcn_s_setprio(1);
        #pragma unroll
        for (int fm = 0; fm < 4; ++fm)
            #pragma unroll
            for (int fn = 0; fn < 4; ++fn)
                acc4[fm][fn] = __builtin_amdgcn_mfma_f32_16x16x32_bf16(af0[fm], bfr[fn], acc4[fm][fn], 0, 0, 0);
        __builtin_amdgcn_s_setprio(0);
        __builtin_amdgcn_s_barrier();

        // ---------- sub-phase 1: stage B(kt+3) | read af4..7 | 16 MFMA | vmcnt ----------
        if (kt <= NKS - 4) STAGEB(kt + 3, ns)
        bf16x8 af1[4];
        #pragma unroll
        for (int fm = 0; fm < 4; ++fm) af1[fm] = *(const bf16x8*)(Ab + raO[fm + 4]);
        __builtin_amdgcn_s_barrier();
        __builtin_amdgcn_s_setprio(1);
        #pragma unroll
        for (int fm = 0; fm < 4; ++fm)
            #pragma unroll
            for (int fn = 0; fn < 4; ++fn)
                acc4[fm + 4][fn] = __builtin_amdgcn_mfma_f32_16x16x32_bf16(af1[fm], bfr[fn], acc4[fm + 4][fn], 0, 0, 0);
        __builtin_amdgcn_s_setprio(0);

        // counted drain: tile kt+1 must be landed for next phase; keep later tiles in flight
        if (kt <= NKS - 4)      { asm volatile("s_waitcnt vmcnt(8)" ::: "memory"); }
        else if (kt == NKS - 3) { asm volatile("s_waitcnt vmcnt(4)" ::: "memory"); }
        else if (kt == NKS - 2) { asm volatile("s_waitcnt vmcnt(0)" ::: "memory"); }
        if (kt < NKS - 1) __builtin_amdgcn_s_barrier();
    }
#undef STAGEA
#undef STAGEB

    // ---- epilogue: d = an + bn - 2*dot ; 3-bandwidth gaussian sum via t = exp(-d/12) ----
    float lsum = 0.f;
    #pragma unroll
    for (int fm = 0; fm < 8; ++fm) {
        const f32x4 anv = *(const f32x4*)(an + bm + wm * 128 + fm * 16 + kg * 4);
        #pragma unroll
        for (int fn = 0; fn < 4; ++fn) {
            const float bnv = bn[bnc + wn * 64 + fn * 16 + fr];
            #pragma unroll
            for (int j = 0; j < 4; ++j) {
                float d  = anv[j] + bnv - 2.0f * acc4[fm][fn][j];
                float t  = __expf(d * (-1.0f / 12.0f));
                float t2 = t * t, t3 = t2 * t;
                lsum += t2 + t3 + t3 * t3;   // bw3 + bw2 + bw1
            }
        }
    }
    #pragma unroll
    for (int off = 32; off; off >>= 1) lsum += __shfl_down(lsum, off, 64);

    // wsum aliased onto slot-0 A-tile: last read of slot 0 was kstep 12; all waves are
    // past kstep 14's closing barrier here, so those reads retired block-wide
    float* wsum = (float*)&Al[0][0];
    if (lane == 0) wsum[w] = lsum;
    __syncthreads();
    if (tid == 0) {
        float bs = 0.f;
        #pragma unroll
        for (int i = 0; i < 8; ++i) bs += wsum[i];
        atomicAdd(acc, (double)(bs * wgt));
    }
}

// ================= launch =================
extern "C" void kernel_launch(void* const* d_in, const int* in_sizes, int n_in,
                              void* d_out, int out_size, void* d_ws, size_t ws_size,
                              hipStream_t stream) {
    const float* x = (const float*)d_in[0];
    const float* y = (const float*)d_in[1];
    float* out = (float*)d_out;
    char* ws = (char*)d_ws;

    const size_t bBytes = (size_t)NR * DIM * 2;      // 8 MiB each
    u16*   xb = (u16*)ws;
    u16*   yb = (u16*)(ws + bBytes);
    float* xn = (float*)(ws + 2 * bBytes);
    float* yn = (float*)(ws + 2 * bBytes + (size_t)NR * 4);
    double* acc = (double*)(ws + 2 * bBytes + 2 * (size_t)NR * 4);

    zero_kernel<<<1, 64, 0, stream>>>(acc);
    conv_bf16<<<(2 * NR) / 4, 256, 0, stream>>>(x, y, xb, yb, xn, yn);
    mmd_bf16<<<2080, 512, 0, stream>>>(xb, yb, xn, yn, acc);
    finalize_kernel<<<1, 64, 0, stream>>>(acc, out);
}

// Round 9
// 207.639 us; speedup vs baseline: 1.0563x; 1.0563x over previous
//
#include <hip/hip_runtime.h>

#define NR  8192
#define DIM 512
#define BM  256
#define NT  8            // K-tiles of 64 bf16 elements

typedef __attribute__((ext_vector_type(8))) short bf16x8;
typedef __attribute__((ext_vector_type(4))) float f32x4;
typedef unsigned short u16;
typedef unsigned int   u32;

__device__ __forceinline__ void gload16(const void* g, void* l) {
    __builtin_amdgcn_global_load_lds((const __attribute__((address_space(1))) void*)g,
                                     (__attribute__((address_space(3))) void*)l,
                                     16, 0, 0);
}

// ================= fp32 -> bf16 + norms (of bf16-rounded values) =================
__global__ __launch_bounds__(256) void conv_bf16(const float* __restrict__ x,
                                                 const float* __restrict__ y,
                                                 u16* __restrict__ xb, u16* __restrict__ yb,
                                                 float* __restrict__ xn, float* __restrict__ yn) {
    int gw = (blockIdx.x * 256 + threadIdx.x) >> 6;
    int lane = threadIdx.x & 63;
    if (gw >= 2 * NR) return;
    int row = (gw < NR) ? gw : gw - NR;
    const float* src = (gw < NR) ? x : y;
    u16*   dst = (gw < NR) ? xb : yb;
    float* nrm = (gw < NR) ? xn : yn;

    const float4* p = (const float4*)(src + (size_t)row * DIM);
    float4 v0 = p[lane * 2], v1 = p[lane * 2 + 1];
    float vv[8] = {v0.x, v0.y, v0.z, v0.w, v1.x, v1.y, v1.z, v1.w};
    u16 us[8]; float s = 0.f;
    #pragma unroll
    for (int i = 0; i < 8; ++i) {
        u32 u = __float_as_uint(vv[i]);
        u16 b = (u16)((u + 0x7FFFu + ((u >> 16) & 1u)) >> 16);   // RNE fp32->bf16
        us[i] = b;
        float bf = __uint_as_float(((u32)b) << 16);
        s += bf * bf;
    }
    *(bf16x8*)(dst + (size_t)row * DIM + lane * 8) = *(const bf16x8*)us;
    #pragma unroll
    for (int off = 32; off; off >>= 1) s += __shfl_down(s, off, 64);
    if (lane == 0) nrm[row] = s;
}

__global__ void zero_kernel(double* acc) {
    if (threadIdx.x == 0 && blockIdx.x == 0) *acc = 0.0;
}

__global__ void finalize_kernel(const double* __restrict__ acc, float* __restrict__ out) {
    if (threadIdx.x == 0 && blockIdx.x == 0) {
        double n2 = (double)NR * (double)NR;
        out[0] = (float)(*acc / n2);
    }
}

// ================= 256^2-tile, 8-wave, 4-phase-per-K-tile, counted-vmcnt =================
// logical grid 2080: [0,528) xx upper-tri, [528,1056) yy upper-tri, [1056,2080) xy (weight -2)
__global__ __launch_bounds__(512, 2) void mmd_bf16(const u16* __restrict__ xb, const u16* __restrict__ yb,
                                                   const float* __restrict__ xn, const float* __restrict__ yn,
                                                   double* __restrict__ acc) {
    int f = (blockIdx.x & 7) * 260 + (blockIdx.x >> 3);   // T1 bijective XCD swizzle
    int z, bi, bj;
    if (f < 1056) {
        z = (f < 528) ? 0 : 1;
        int t = (f < 528) ? f : f - 528;
        int r = (int)((sqrtf(8.f * t + 1.f) - 1.f) * 0.5f);
        while ((r + 1) * (r + 2) / 2 <= t) ++r;
        while (r * (r + 1) / 2 > t) --r;
        bi = t - r * (r + 1) / 2;   // bi <= bj
        bj = r;
    } else {
        z = 2; int t = f - 1056; bi = t >> 5; bj = t & 31;
    }
    const u16*   A  = (z == 1) ? yb : xb;
    const u16*   B  = (z == 0) ? xb : yb;
    const float* an = (z == 1) ? yn : xn;
    const float* bn = (z == 0) ? xn : yn;
    const float wgt = (z == 2) ? -2.f : ((bi == bj) ? 1.f : 2.f);
    const int bm = bi * BM, bnc = bj * BM;

    // double-buffered A,B tiles: 2 * 2 * 256*64 * 2B = 128 KiB
    __shared__ __align__(16) u16 Al[2][BM * 64];
    __shared__ __align__(16) u16 Bl[2][BM * 64];

    const int tid = threadIdx.x, w = tid >> 6, lane = tid & 63;
    const int wm = w >> 2, wn = w & 3;            // 2x4 wave grid; per-wave 128x64 out
    const int srow = lane >> 3;                   // 0..7
    const int dslot = (lane & 7) ^ srow;          // pre-swizzled source 16B slot
    const int fr = lane & 15, kg = lane >> 4;

    int raO[8], rbO[4];
    #pragma unroll
    for (int fm = 0; fm < 8; ++fm) raO[fm] = (wm * 128 + fm * 16 + fr) * 64;
    #pragma unroll
    for (int fn = 0; fn < 4; ++fn) rbO[fn] = (wn * 64 + fn * 16 + fr) * 64;
    const int s0 = ((kg)     ^ (lane & 7)) * 8;   // kstep0 swizzled slot offset (elems)
    const int s1 = ((4 + kg) ^ (lane & 7)) * 8;   // kstep1

    f32x4 acc4[8][4];
    #pragma unroll
    for (int i = 0; i < 8; ++i)
        #pragma unroll
        for (int j = 0; j < 4; ++j)
            acc4[i][j] = {0.f, 0.f, 0.f, 0.f};

    const size_t aRow = (size_t)(bm  + w * 32 + srow) * DIM + dslot * 8;
    const size_t bRow = (size_t)(bnc + w * 32 + srow) * DIM + dslot * 8;

#define STAGE(kt, buf)                                                              \
    {                                                                               \
        _Pragma("unroll")                                                           \
        for (int q = 0; q < 4; ++q) {                                               \
            const int rb_ = w * 32 + q * 8;                                         \
            gload16(A + aRow + (size_t)q * 8 * DIM + (kt) * 64, &Al[buf][rb_ * 64]);\
            gload16(B + bRow + (size_t)q * 8 * DIM + (kt) * 64, &Bl[buf][rb_ * 64]);\
        }                                                                           \
    }

#define LDA(fm_, so_) (*(const bf16x8*)(Ab + raO[fm_] + (so_)))
#define LDB(fn_, so_) (*(const bf16x8*)(Bb + rbO[fn_] + (so_)))

#define PH_ENTER                                                    \
    __builtin_amdgcn_s_barrier();                                   \
    asm volatile("s_waitcnt lgkmcnt(0)" ::: "memory");              \
    __builtin_amdgcn_sched_barrier(0);                              \
    __builtin_amdgcn_s_setprio(1);

#define MFMAQ(MH, NH, BF)                                                           \
    _Pragma("unroll")                                                               \
    for (int fp = 0; fp < 4; ++fp)                                                  \
        _Pragma("unroll")                                                           \
        for (int fq = 0; fq < 2; ++fq) {                                            \
            acc4[(MH)*4+fp][(NH)*2+fq] = __builtin_amdgcn_mfma_f32_16x16x32_bf16(   \
                af[fp][0], BF[fq][0], acc4[(MH)*4+fp][(NH)*2+fq], 0, 0, 0);         \
            acc4[(MH)*4+fp][(NH)*2+fq] = __builtin_amdgcn_mfma_f32_16x16x32_bf16(   \
                af[fp][1], BF[fq][1], acc4[(MH)*4+fp][(NH)*2+fq], 0, 0, 0);         \
        }

    // prologue: stage tiles 0 and 1; wait tile 0 (tile 1's 8 loads stay in flight)
    STAGE(0, 0)
    STAGE(1, 1)
    asm volatile("s_waitcnt vmcnt(8)" ::: "memory");
    __builtin_amdgcn_s_barrier();

    #pragma unroll
    for (int kt = 0; kt < NT; ++kt) {
        const int cur = kt & 1;
        const u16* Ab = &Al[cur][0];
        const u16* Bb = &Bl[cur][0];
        bf16x8 af[4][2], bf0[2][2], bf1[2][2];

        // ---- phase 0: quadrant (0,0) | reads af(mh=0) 8 + bf0 4 ----
        #pragma unroll
        for (int i = 0; i < 4; ++i) { af[i][0] = LDA(i, s0); af[i][1] = LDA(i, s1); }
        #pragma unroll
        for (int j = 0; j < 2; ++j) { bf0[j][0] = LDB(j, s0); bf0[j][1] = LDB(j, s1); }
        PH_ENTER
        MFMAQ(0, 0, bf0)
        __builtin_amdgcn_s_setprio(0);
        __builtin_amdgcn_s_barrier();

        // ---- phase 1: quadrant (0,1) | reads bf1 4 (af held) ----
        #pragma unroll
        for (int j = 0; j < 2; ++j) { bf1[j][0] = LDB(2 + j, s0); bf1[j][1] = LDB(2 + j, s1); }
        PH_ENTER
        MFMAQ(0, 1, bf1)
        __builtin_amdgcn_s_setprio(0);
        __builtin_amdgcn_s_barrier();

        // ---- phase 2: quadrant (1,1) | reads af(mh=1) 8 (bf1 held) ----
        #pragma unroll
        for (int i = 0; i < 4; ++i) { af[i][0] = LDA(4 + i, s0); af[i][1] = LDA(4 + i, s1); }
        PH_ENTER
        MFMAQ(1, 1, bf1)
        __builtin_amdgcn_s_setprio(0);
        __builtin_amdgcn_s_barrier();

        // ---- phase 3: quadrant (1,0) | 0 reads (bf0 held) | stage kt+2 ----
        // all LDS reads of buf[cur] retired block-wide at phase 2's closing barrier;
        // phase 3 is register-only, so refilling buf[cur] here is race-free
        if (kt + 2 < NT) STAGE(kt + 2, cur)
        PH_ENTER
        MFMAQ(1, 0, bf0)
        __builtin_amdgcn_s_setprio(0);

        if (kt + 1 < NT) {
            if (kt < NT - 2) {
                asm volatile("s_waitcnt vmcnt(8)" ::: "memory");   // tile kt+1 landed; kt+2 in flight
            } else {
                asm volatile("s_waitcnt vmcnt(0)" ::: "memory");   // last refill: drain
            }
            __builtin_amdgcn_s_barrier();
        }
    }
#undef STAGE
#undef LDA
#undef LDB
#undef PH_ENTER
#undef MFMAQ

    // ---- epilogue: d = an + bn - 2*dot ; 3-bandwidth gaussian sum via t = exp(-d/12) ----
    float lsum = 0.f;
    #pragma unroll
    for (int fm = 0; fm < 8; ++fm) {
        const f32x4 anv = *(const f32x4*)(an + bm + wm * 128 + fm * 16 + kg * 4);
        #pragma unroll
        for (int fn = 0; fn < 4; ++fn) {
            const float bnv = bn[bnc + wn * 64 + fn * 16 + fr];
            #pragma unroll
            for (int j = 0; j < 4; ++j) {
                float d  = anv[j] + bnv - 2.0f * acc4[fm][fn][j];
                float t  = __expf(d * (-1.0f / 12.0f));
                float t2 = t * t, t3 = t2 * t;
                lsum += t2 + t3 + t3 * t3;   // bw3 + bw2 + bw1
            }
        }
    }
    #pragma unroll
    for (int off = 32; off; off >>= 1) lsum += __shfl_down(lsum, off, 64);

    // wsum aliased onto buf0 A-tile: buf0's last reads (kt=6) retired at kt=6's
    // trailing barrier; kt=7 reads buf1 only; __syncthreads below orders the write
    float* wsum = (float*)&Al[0][0];
    if (lane == 0) wsum[w] = lsum;
    __syncthreads();
    if (tid == 0) {
        float bs = 0.f;
        #pragma unroll
        for (int i = 0; i < 8; ++i) bs += wsum[i];
        atomicAdd(acc, (double)(bs * wgt));
    }
}

// ================= launch =================
extern "C" void kernel_launch(void* const* d_in, const int* in_sizes, int n_in,
                              void* d_out, int out_size, void* d_ws, size_t ws_size,
                              hipStream_t stream) {
    const float* x = (const float*)d_in[0];
    const float* y = (const float*)d_in[1];
    float* out = (float*)d_out;
    char* ws = (char*)d_ws;

    const size_t bBytes = (size_t)NR * DIM * 2;      // 8 MiB each
    u16*   xb = (u16*)ws;
    u16*   yb = (u16*)(ws + bBytes);
    float* xn = (float*)(ws + 2 * bBytes);
    float* yn = (float*)(ws + 2 * bBytes + (size_t)NR * 4);
    double* acc = (double*)(ws + 2 * bBytes + 2 * (size_t)NR * 4);

    zero_kernel<<<1, 64, 0, stream>>>(acc);
    conv_bf16<<<(2 * NR) / 4, 256, 0, stream>>>(x, y, xb, yb, xn, yn);
    mmd_bf16<<<2080, 512, 0, stream>>>(xb, yb, xn, yn, acc);
    finalize_kernel<<<1, 64, 0, stream>>>(acc, out);
}

// Round 10
// 204.903 us; speedup vs baseline: 1.0704x; 1.0134x over previous
//
#include <hip/hip_runtime.h>

#define NR  8192
#define DIM 512
#define BM  128          // square tile
#define NT  8            // K-tiles of 64 bf16 elements

typedef __attribute__((ext_vector_type(8))) short bf16x8;
typedef __attribute__((ext_vector_type(4))) float f32x4;
typedef unsigned short u16;
typedef unsigned int   u32;

__device__ __forceinline__ void gload16(const void* g, void* l) {
    __builtin_amdgcn_global_load_lds((const __attribute__((address_space(1))) void*)g,
                                     (__attribute__((address_space(3))) void*)l,
                                     16, 0, 0);
}

// ================= fp32 -> bf16 + norms (of bf16-rounded values) =================
__global__ __launch_bounds__(256) void conv_bf16(const float* __restrict__ x,
                                                 const float* __restrict__ y,
                                                 u16* __restrict__ xb, u16* __restrict__ yb,
                                                 float* __restrict__ xn, float* __restrict__ yn) {
    int gw = (blockIdx.x * 256 + threadIdx.x) >> 6;
    int lane = threadIdx.x & 63;
    if (gw >= 2 * NR) return;
    int row = (gw < NR) ? gw : gw - NR;
    const float* src = (gw < NR) ? x : y;
    u16*   dst = (gw < NR) ? xb : yb;
    float* nrm = (gw < NR) ? xn : yn;

    const float4* p = (const float4*)(src + (size_t)row * DIM);
    float4 v0 = p[lane * 2], v1 = p[lane * 2 + 1];
    float vv[8] = {v0.x, v0.y, v0.z, v0.w, v1.x, v1.y, v1.z, v1.w};
    u16 us[8]; float s = 0.f;
    #pragma unroll
    for (int i = 0; i < 8; ++i) {
        u32 u = __float_as_uint(vv[i]);
        u16 b = (u16)((u + 0x7FFFu + ((u >> 16) & 1u)) >> 16);   // RNE fp32->bf16
        us[i] = b;
        float bf = __uint_as_float(((u32)b) << 16);
        s += bf * bf;
    }
    *(bf16x8*)(dst + (size_t)row * DIM + lane * 8) = *(const bf16x8*)us;
    #pragma unroll
    for (int off = 32; off; off >>= 1) s += __shfl_down(s, off, 64);
    if (lane == 0) nrm[row] = s;
}

__global__ void zero_kernel(double* acc) {
    if (threadIdx.x == 0 && blockIdx.x == 0) *acc = 0.0;
}

__global__ void finalize_kernel(const double* __restrict__ acc, float* __restrict__ out) {
    if (threadIdx.x == 0 && blockIdx.x == 0) {
        double n2 = (double)NR * (double)NR;
        out[0] = (float)(*acc / n2);
    }
}

// ================= 128^2-tile, 4-wave, counted-vmcnt, 2 blocks/CU =================
// logical grid 8256: [0,2080) xx upper-tri, [2080,4160) yy upper-tri, [4160,8256) xy (weight -2)
__global__ __launch_bounds__(256, 2) void mmd_bf16(const u16* __restrict__ xb, const u16* __restrict__ yb,
                                                   const float* __restrict__ xn, const float* __restrict__ yn,
                                                   double* __restrict__ acc) {
    int f = (blockIdx.x & 7) * 1032 + (blockIdx.x >> 3);   // T1 bijective XCD swizzle (8256%8==0)
    int z, bi, bj;
    if (f < 4160) {
        z = (f < 2080) ? 0 : 1;
        int t = (f < 2080) ? f : f - 2080;
        int r = (int)((sqrtf(8.f * t + 1.f) - 1.f) * 0.5f);
        while ((r + 1) * (r + 2) / 2 <= t) ++r;
        while (r * (r + 1) / 2 > t) --r;
        bi = t - r * (r + 1) / 2;   // bi <= bj
        bj = r;
    } else {
        z = 2; int t = f - 4160; bi = t >> 6; bj = t & 63;
    }
    const u16*   A  = (z == 1) ? yb : xb;
    const u16*   B  = (z == 0) ? xb : yb;
    const float* an = (z == 1) ? yn : xn;
    const float* bn = (z == 0) ? xn : yn;
    const float wgt = (z == 2) ? -2.f : ((bi == bj) ? 1.f : 2.f);
    const int bm = bi * BM, bnc = bj * BM;

    // double-buffered A,B tiles: 2 bufs * 2 arrays * 128 rows * 64 elems * 2B = 64 KiB
    __shared__ __align__(16) u16 Al[2][BM * 64];
    __shared__ __align__(16) u16 Bl[2][BM * 64];

    const int tid = threadIdx.x, w = tid >> 6, lane = tid & 63;
    const int wm = w >> 1, wn = w & 1;            // 2x2 wave grid; per-wave 64x64 out
    const int srow = lane >> 3;                   // 0..7
    const int dslot = (lane & 7) ^ srow;          // pre-swizzled source 16B slot
    const int fr = lane & 15, kg = lane >> 4;

    int raO[4], rbO[4];
    #pragma unroll
    for (int fm = 0; fm < 4; ++fm) raO[fm] = (wm * 64 + fm * 16 + fr) * 64;
    #pragma unroll
    for (int fn = 0; fn < 4; ++fn) rbO[fn] = (wn * 64 + fn * 16 + fr) * 64;
    const int s0 = ((kg)     ^ (lane & 7)) * 8;   // kstep0 swizzled slot offset (elems)
    const int s1 = ((4 + kg) ^ (lane & 7)) * 8;   // kstep1

    f32x4 acc4[4][4];
    #pragma unroll
    for (int i = 0; i < 4; ++i)
        #pragma unroll
        for (int j = 0; j < 4; ++j)
            acc4[i][j] = {0.f, 0.f, 0.f, 0.f};

    // staging: wave w covers rows w*32 + q*8 + srow (q=0..3); 4 waves -> 128 rows
    const size_t aRow = (size_t)(bm  + w * 32 + srow) * DIM + dslot * 8;
    const size_t bRow = (size_t)(bnc + w * 32 + srow) * DIM + dslot * 8;

#define STAGE(kt, buf)                                                              \
    {                                                                               \
        _Pragma("unroll")                                                           \
        for (int q = 0; q < 4; ++q) {                                               \
            const int rb_ = w * 32 + q * 8;                                         \
            gload16(A + aRow + (size_t)q * 8 * DIM + (kt) * 64, &Al[buf][rb_ * 64]);\
            gload16(B + bRow + (size_t)q * 8 * DIM + (kt) * 64, &Bl[buf][rb_ * 64]);\
        }                                                                           \
    }

    // prologue: stage tiles 0 and 1; wait tile 0 (tile 1's 8 loads stay in flight)
    STAGE(0, 0)
    STAGE(1, 1)
    asm volatile("s_waitcnt vmcnt(8)" ::: "memory");
    __builtin_amdgcn_s_barrier();

    #pragma unroll
    for (int kt = 0; kt < NT; ++kt) {
        const int cur = kt & 1;
        const u16* Ab = &Al[cur][0];
        const u16* Bb = &Bl[cur][0];

        #pragma unroll
        for (int ph = 0; ph < 2; ++ph) {
            const int so = ph ? s1 : s0;
            bf16x8 af[4], bfr[4];
            #pragma unroll
            for (int fm = 0; fm < 4; ++fm) af[fm] = *(const bf16x8*)(Ab + raO[fm] + so);
            #pragma unroll
            for (int fn = 0; fn < 4; ++fn) bfr[fn] = *(const bf16x8*)(Bb + rbO[fn] + so);
            __builtin_amdgcn_s_setprio(1);
            #pragma unroll
            for (int fm = 0; fm < 4; ++fm)
                #pragma unroll
                for (int fn = 0; fn < 4; ++fn)
                    acc4[fm][fn] = __builtin_amdgcn_mfma_f32_16x16x32_bf16(af[fm], bfr[fn], acc4[fm][fn], 0, 0, 0);
            __builtin_amdgcn_s_setprio(0);
        }

        if (kt + 1 < NT) {
            asm volatile("s_waitcnt lgkmcnt(0)" ::: "memory");
            __builtin_amdgcn_s_barrier();              // buf[cur] reads retired block-wide
            if (kt + 2 < NT) {
                STAGE(kt + 2, cur)                     // refill just-freed buffer
                asm volatile("s_waitcnt vmcnt(8)" ::: "memory");  // tile kt+1 landed
            } else {
                asm volatile("s_waitcnt vmcnt(0)" ::: "memory");  // last tile: drain
            }
            __builtin_amdgcn_s_barrier();
        }
    }
#undef STAGE

    // ---- epilogue: d = an + bn - 2*dot ; 3-bandwidth gaussian sum via t = exp(-d/12) ----
    float lsum = 0.f;
    #pragma unroll
    for (int fm = 0; fm < 4; ++fm) {
        const f32x4 anv = *(const f32x4*)(an + bm + wm * 64 + fm * 16 + kg * 4);
        #pragma unroll
        for (int fn = 0; fn < 4; ++fn) {
            const float bnv = bn[bnc + wn * 64 + fn * 16 + fr];
            #pragma unroll
            for (int j = 0; j < 4; ++j) {
                float d  = anv[j] + bnv - 2.0f * acc4[fm][fn][j];
                float t  = __expf(d * (-1.0f / 12.0f));
                float t2 = t * t, t3 = t2 * t;
                lsum += t2 + t3 + t3 * t3;   // bw3 + bw2 + bw1
            }
        }
    }
    #pragma unroll
    for (int off = 32; off; off >>= 1) lsum += __shfl_down(lsum, off, 64);

    // wsum aliased onto buf0 A-tile (kt=7 read buf1 only; __syncthreads orders the write)
    float* wsum = (float*)&Al[0][0];
    if (lane == 0) wsum[w] = lsum;
    __syncthreads();
    if (tid == 0) {
        float bs = wsum[0] + wsum[1] + wsum[2] + wsum[3];
        atomicAdd(acc, (double)(bs * wgt));
    }
}

// ================= launch =================
extern "C" void kernel_launch(void* const* d_in, const int* in_sizes, int n_in,
                              void* d_out, int out_size, void* d_ws, size_t ws_size,
                              hipStream_t stream) {
    const float* x = (const float*)d_in[0];
    const float* y = (const float*)d_in[1];
    float* out = (float*)d_out;
    char* ws = (char*)d_ws;

    const size_t bBytes = (size_t)NR * DIM * 2;      // 8 MiB each
    u16*   xb = (u16*)ws;
    u16*   yb = (u16*)(ws + bBytes);
    float* xn = (float*)(ws + 2 * bBytes);
    float* yn = (float*)(ws + 2 * bBytes + (size_t)NR * 4);
    double* acc = (double*)(ws + 2 * bBytes + 2 * (size_t)NR * 4);

    zero_kernel<<<1, 64, 0, stream>>>(acc);
    conv_bf16<<<(2 * NR) / 4, 256, 0, stream>>>(x, y, xb, yb, xn, yn);
    mmd_bf16<<<8256, 256, 0, stream>>>(xb, yb, xn, yn, acc);
    finalize_kernel<<<1, 64, 0, stream>>>(acc, out);
}

// Round 11
// 202.426 us; speedup vs baseline: 1.0835x; 1.0122x over previous
//
#include <hip/hip_runtime.h>

#define NR  8192
#define DIM 512
#define BM  256
#define NT  8            // K-tiles of 64 bf16 elements

typedef __attribute__((ext_vector_type(8))) short bf16x8;
typedef __attribute__((ext_vector_type(4))) float f32x4;
typedef unsigned short u16;
typedef unsigned int   u32;

__device__ __forceinline__ void gload16(const void* g, void* l) {
    __builtin_amdgcn_global_load_lds((const __attribute__((address_space(1))) void*)g,
                                     (__attribute__((address_space(3))) void*)l,
                                     16, 0, 0);
}

// ================= fp32 -> bf16 + norms (of bf16-rounded values) =================
__global__ __launch_bounds__(256) void conv_bf16(const float* __restrict__ x,
                                                 const float* __restrict__ y,
                                                 u16* __restrict__ xb, u16* __restrict__ yb,
                                                 float* __restrict__ xn, float* __restrict__ yn) {
    int gw = (blockIdx.x * 256 + threadIdx.x) >> 6;
    int lane = threadIdx.x & 63;
    if (gw >= 2 * NR) return;
    int row = (gw < NR) ? gw : gw - NR;
    const float* src = (gw < NR) ? x : y;
    u16*   dst = (gw < NR) ? xb : yb;
    float* nrm = (gw < NR) ? xn : yn;

    const float4* p = (const float4*)(src + (size_t)row * DIM);
    float4 v0 = p[lane * 2], v1 = p[lane * 2 + 1];
    float vv[8] = {v0.x, v0.y, v0.z, v0.w, v1.x, v1.y, v1.z, v1.w};
    u16 us[8]; float s = 0.f;
    #pragma unroll
    for (int i = 0; i < 8; ++i) {
        u32 u = __float_as_uint(vv[i]);
        u16 b = (u16)((u + 0x7FFFu + ((u >> 16) & 1u)) >> 16);   // RNE fp32->bf16
        us[i] = b;
        float bf = __uint_as_float(((u32)b) << 16);
        s += bf * bf;
    }
    *(bf16x8*)(dst + (size_t)row * DIM + lane * 8) = *(const bf16x8*)us;
    #pragma unroll
    for (int off = 32; off; off >>= 1) s += __shfl_down(s, off, 64);
    if (lane == 0) nrm[row] = s;
}

__global__ void zero_kernel(double* acc) {
    if (threadIdx.x == 0 && blockIdx.x == 0) *acc = 0.0;
}

__global__ void finalize_kernel(const double* __restrict__ acc, float* __restrict__ out) {
    if (threadIdx.x == 0 && blockIdx.x == 0) {
        double n2 = (double)NR * (double)NR;
        out[0] = (float)(*acc / n2);
    }
}

// triangular + xy decode: f in [0,2080)
__device__ __forceinline__ void tri_decode(int f, int& z, int& bi, int& bj) {
    if (f < 1056) {
        z = (f < 528) ? 0 : 1;
        int t = (f < 528) ? f : f - 528;
        int r = (int)((sqrtf(8.f * t + 1.f) - 1.f) * 0.5f);
        while ((r + 1) * (r + 2) / 2 <= t) ++r;
        while (r * (r + 1) / 2 > t) --r;
        bi = t - r * (r + 1) / 2;   // bi <= bj
        bj = r;
    } else {
        z = 2; int t = f - 1056; bi = t >> 5; bj = t & 31;
    }
}

// ================= persistent 256-block, 256^2-tile, 8-wave, counted-vmcnt =================
__global__ __launch_bounds__(512, 1) void mmd_bf16(const u16* __restrict__ xb, const u16* __restrict__ yb,
                                                   const float* __restrict__ xn, const float* __restrict__ yn,
                                                   double* __restrict__ acc) {
    __shared__ __align__(16) u16 Al[2][BM * 64];
    __shared__ __align__(16) u16 Bl[2][BM * 64];
    __shared__ float wsum[8];

    // chunked persistent assignment: XCD k (blocks p%8==k) gets contiguous f-range
    const int p  = blockIdx.x;                 // 0..255
    const int pp = (p & 7) * 32 + (p >> 3);
    const int f0 = (pp * 65) >> 3;             // 2080/256 = 65/8
    const int f1 = ((pp + 1) * 65) >> 3;

    const int tid = threadIdx.x, w = tid >> 6, lane = tid & 63;
    const int wm = w >> 2, wn = w & 3;         // 2x4 wave grid; per-wave 128x64 out
    const int srow = lane >> 3;                // 0..7
    const int dslot = (lane & 7) ^ srow;       // pre-swizzled source 16B slot
    const int fr = lane & 15, kg = lane >> 4;

    int raO[8], rbO[4];
    #pragma unroll
    for (int fm = 0; fm < 8; ++fm) raO[fm] = (wm * 128 + fm * 16 + fr) * 64;
    #pragma unroll
    for (int fn = 0; fn < 4; ++fn) rbO[fn] = (wn * 64 + fn * 16 + fr) * 64;
    const int s0 = ((kg)     ^ (lane & 7)) * 8;
    const int s1 = ((4 + kg) ^ (lane & 7)) * 8;

#define STAGE1(P_, RB_, KT_, DST_)                                                  \
    {                                                                               \
        _Pragma("unroll")                                                           \
        for (int q = 0; q < 4; ++q) {                                               \
            const int rb_ = w * 32 + q * 8;                                         \
            gload16(P_ + RB_ + (size_t)q * 8 * DIM + (KT_) * 64, &DST_[rb_ * 64]);  \
        }                                                                           \
    }

    // current-tile params
    int z, bi, bj; tri_decode(f0, z, bi, bj);
    const u16*   A  = (z == 1) ? yb : xb;
    const u16*   B  = (z == 0) ? xb : yb;
    const float* an = (z == 1) ? yn : xn;
    const float* bn = (z == 0) ? xn : yn;
    float wgt = (z == 2) ? -2.f : ((bi == bj) ? 1.f : 2.f);
    int bm = bi * BM, bnc = bj * BM;
    size_t aRow = (size_t)(bm  + w * 32 + srow) * DIM + dslot * 8;
    size_t bRow = (size_t)(bnc + w * 32 + srow) * DIM + dslot * 8;

    // cold prologue: stage tiles 0,1 of the first f
    STAGE1(A, aRow, 0, Al[0]) STAGE1(B, bRow, 0, Bl[0])
    STAGE1(A, aRow, 1, Al[1]) STAGE1(B, bRow, 1, Bl[1])

    for (int f = f0; f < f1; ++f) {
        const bool hasNext = (f + 1 < f1);
        // next-tile params (staging of next tile is spliced into this tile's K-loop)
        const u16 *nA = A, *nB = B; const float *nan_ = an, *nbn_ = bn;
        float nwgt = wgt; int nbm = bm, nbnc = bnc; size_t naRow = aRow, nbRow = bRow;
        if (hasNext) {
            int z2, bi2, bj2; tri_decode(f + 1, z2, bi2, bj2);
            nA  = (z2 == 1) ? yb : xb;
            nB  = (z2 == 0) ? xb : yb;
            nan_ = (z2 == 1) ? yn : xn;
            nbn_ = (z2 == 0) ? xn : yn;
            nwgt = (z2 == 2) ? -2.f : ((bi2 == bj2) ? 1.f : 2.f);
            nbm = bi2 * BM; nbnc = bj2 * BM;
            naRow = (size_t)(nbm  + w * 32 + srow) * DIM + dslot * 8;
            nbRow = (size_t)(nbnc + w * 32 + srow) * DIM + dslot * 8;
        }

        // tile-0 of this f landed (tile-1's 8 loads may stay in flight)
        asm volatile("s_waitcnt vmcnt(8)" ::: "memory");
        __builtin_amdgcn_s_barrier();

        f32x4 acc4[8][4];
        #pragma unroll
        for (int i = 0; i < 8; ++i)
            #pragma unroll
            for (int j = 0; j < 4; ++j)
                acc4[i][j] = {0.f, 0.f, 0.f, 0.f};

        #pragma unroll
        for (int kt = 0; kt < NT; ++kt) {
            const int cur = kt & 1;
            const u16* Ab = &Al[cur][0];
            const u16* Bb = &Bl[cur][0];

            #pragma unroll
            for (int ph = 0; ph < 2; ++ph) {
                const int so = ph ? s1 : s0;
                bf16x8 af[8], bfr[4];
                #pragma unroll
                for (int fm = 0; fm < 8; ++fm) af[fm] = *(const bf16x8*)(Ab + raO[fm] + so);
                #pragma unroll
                for (int fn = 0; fn < 4; ++fn) bfr[fn] = *(const bf16x8*)(Bb + rbO[fn] + so);
                #pragma unroll
                for (int fm = 0; fm < 8; ++fm)
                    #pragma unroll
                    for (int fn = 0; fn < 4; ++fn)
                        acc4[fm][fn] = __builtin_amdgcn_mfma_f32_16x16x32_bf16(af[fm], bfr[fn], acc4[fm][fn], 0, 0, 0);
            }

            if (kt + 1 < NT) {
                asm volatile("s_waitcnt lgkmcnt(0)" ::: "memory");
                __builtin_amdgcn_s_barrier();              // buf[cur] reads retired block-wide
                if (kt + 2 < NT) {
                    STAGE1(A, aRow, kt + 2, Al[cur]) STAGE1(B, bRow, kt + 2, Bl[cur])
                    asm volatile("s_waitcnt vmcnt(8)" ::: "memory");   // tile kt+1 landed
                } else {
                    // kt==6 (cur==0): buf0 free -> prefetch NEXT f's K-tile 0 here
                    if (hasNext) {
                        STAGE1(nA, naRow, 0, Al[0]) STAGE1(nB, nbRow, 0, Bl[0])
                        asm volatile("s_waitcnt vmcnt(8)" ::: "memory");  // tile 7 landed; next0 flies
                    } else {
                        asm volatile("s_waitcnt vmcnt(0)" ::: "memory");  // drain: tile 7 landed
                    }
                }
                __builtin_amdgcn_s_barrier();
            }
        }

        // kt=7 read buf1; retire its reads block-wide, then prefetch next f's K-tile 1
        asm volatile("s_waitcnt lgkmcnt(0)" ::: "memory");
        __builtin_amdgcn_s_barrier();
        if (hasNext) { STAGE1(nA, nbRow - nbRow + naRow, 1, Al[1]) STAGE1(nB, nbRow, 1, Bl[1]) }

        // ---- epilogue (VALU) overlaps the in-flight next-tile staging ----
        float lsum = 0.f;
        #pragma unroll
        for (int fm = 0; fm < 8; ++fm) {
            const f32x4 anv = *(const f32x4*)(an + bm + wm * 128 + fm * 16 + kg * 4);
            #pragma unroll
            for (int fn = 0; fn < 4; ++fn) {
                const float bnv = bn[bnc + wn * 64 + fn * 16 + fr];
                #pragma unroll
                for (int j = 0; j < 4; ++j) {
                    float d  = anv[j] + bnv - 2.0f * acc4[fm][fn][j];
                    float t  = __expf(d * (-1.0f / 12.0f));
                    float t2 = t * t, t3 = t2 * t;
                    lsum += t2 + t3 + t3 * t3;   // bw3 + bw2 + bw1
                }
            }
        }
        #pragma unroll
        for (int off = 32; off; off >>= 1) lsum += __shfl_down(lsum, off, 64);
        if (lane == 0) wsum[w] = lsum;
        asm volatile("s_waitcnt lgkmcnt(0)" ::: "memory");
        __builtin_amdgcn_s_barrier();
        if (tid == 0) {
            float bs = 0.f;
            #pragma unroll
            for (int i = 0; i < 8; ++i) bs += wsum[i];
            atomicAdd(acc, (double)(bs * wgt));
        }

        // rotate params for next iteration
        A = nA; B = nB; an = nan_; bn = nbn_; wgt = nwgt;
        bm = nbm; bnc = nbnc; aRow = naRow; bRow = nbRow;
    }
#undef STAGE1
}

// ================= launch =================
extern "C" void kernel_launch(void* const* d_in, const int* in_sizes, int n_in,
                              void* d_out, int out_size, void* d_ws, size_t ws_size,
                              hipStream_t stream) {
    const float* x = (const float*)d_in[0];
    const float* y = (const float*)d_in[1];
    float* out = (float*)d_out;
    char* ws = (char*)d_ws;

    const size_t bBytes = (size_t)NR * DIM * 2;      // 8 MiB each
    u16*   xb = (u16*)ws;
    u16*   yb = (u16*)(ws + bBytes);
    float* xn = (float*)(ws + 2 * bBytes);
    float* yn = (float*)(ws + 2 * bBytes + (size_t)NR * 4);
    double* acc = (double*)(ws + 2 * bBytes + 2 * (size_t)NR * 4);

    zero_kernel<<<1, 64, 0, stream>>>(acc);
    conv_bf16<<<(2 * NR) / 4, 256, 0, stream>>>(x, y, xb, yb, xn, yn);
    mmd_bf16<<<256, 512, 0, stream>>>(xb, yb, xn, yn, acc);
    finalize_kernel<<<1, 64, 0, stream>>>(acc, out);
}

// Round 12
// 193.987 us; speedup vs baseline: 1.1306x; 1.0435x over previous
//
#include <hip/hip_runtime.h>

#define NR  8192
#define DIM 512
#define BM  256          // square tile
#define NT  8            // K-tiles of 64 bf16 elements

typedef __attribute__((ext_vector_type(8))) short bf16x8;
typedef __attribute__((ext_vector_type(4))) float f32x4;
typedef unsigned short u16;
typedef unsigned int   u32;

__device__ __forceinline__ void gload16(const void* g, void* l) {
    __builtin_amdgcn_global_load_lds((const __attribute__((address_space(1))) void*)g,
                                     (__attribute__((address_space(3))) void*)l,
                                     16, 0, 0);
}

// ================= fp32 -> bf16 + norms (of bf16-rounded values) =================
__global__ __launch_bounds__(256) void conv_bf16(const float* __restrict__ x,
                                                 const float* __restrict__ y,
                                                 u16* __restrict__ xb, u16* __restrict__ yb,
                                                 float* __restrict__ xn, float* __restrict__ yn) {
    int gw = (blockIdx.x * 256 + threadIdx.x) >> 6;
    int lane = threadIdx.x & 63;
    if (gw >= 2 * NR) return;
    int row = (gw < NR) ? gw : gw - NR;
    const float* src = (gw < NR) ? x : y;
    u16*   dst = (gw < NR) ? xb : yb;
    float* nrm = (gw < NR) ? xn : yn;

    const float4* p = (const float4*)(src + (size_t)row * DIM);
    float4 v0 = p[lane * 2], v1 = p[lane * 2 + 1];
    float vv[8] = {v0.x, v0.y, v0.z, v0.w, v1.x, v1.y, v1.z, v1.w};
    u16 us[8]; float s = 0.f;
    #pragma unroll
    for (int i = 0; i < 8; ++i) {
        u32 u = __float_as_uint(vv[i]);
        u16 b = (u16)((u + 0x7FFFu + ((u >> 16) & 1u)) >> 16);   // RNE fp32->bf16
        us[i] = b;
        float bf = __uint_as_float(((u32)b) << 16);
        s += bf * bf;
    }
    *(bf16x8*)(dst + (size_t)row * DIM + lane * 8) = *(const bf16x8*)us;
    #pragma unroll
    for (int off = 32; off; off >>= 1) s += __shfl_down(s, off, 64);
    if (lane == 0) nrm[row] = s;
}

__global__ void zero_kernel(double* acc) {
    if (threadIdx.x == 0 && blockIdx.x == 0) *acc = 0.0;
}

__global__ void finalize_kernel(const double* __restrict__ acc, float* __restrict__ out) {
    if (threadIdx.x == 0 && blockIdx.x == 0) {
        double n2 = (double)NR * (double)NR;
        out[0] = (float)(*acc / n2);
    }
}

// ================= 256^2-tile, 8-wave, counted-vmcnt, anti-phase wave skew =================
// logical grid 2080: [0,528) xx upper-tri, [528,1056) yy upper-tri, [1056,2080) xy (weight -2)
__global__ __launch_bounds__(512, 2) void mmd_bf16(const u16* __restrict__ xb, const u16* __restrict__ yb,
                                                   const float* __restrict__ xn, const float* __restrict__ yn,
                                                   double* __restrict__ acc) {
    // T1: XCD-aware swizzle (2080 % 8 == 0 -> simple bijective form)
    int f = (blockIdx.x & 7) * 260 + (blockIdx.x >> 3);
    int z, bi, bj;
    if (f < 1056) {
        z = (f < 528) ? 0 : 1;
        int t = (f < 528) ? f : f - 528;
        int r = (int)((sqrtf(8.f * t + 1.f) - 1.f) * 0.5f);
        while ((r + 1) * (r + 2) / 2 <= t) ++r;
        while (r * (r + 1) / 2 > t) --r;
        bi = t - r * (r + 1) / 2;   // bi <= bj
        bj = r;
    } else {
        z = 2; int t = f - 1056; bi = t >> 5; bj = t & 31;
    }
    const u16*   A  = (z == 1) ? yb : xb;
    const u16*   B  = (z == 0) ? xb : yb;
    const float* an = (z == 1) ? yn : xn;
    const float* bn = (z == 0) ? xn : yn;
    const float wgt = (z == 2) ? -2.f : ((bi == bj) ? 1.f : 2.f);
    const int bm = bi * BM, bnc = bj * BM;

    // double-buffered A,B tiles: 2 * 2 * 256*64 * 2B = 128 KiB
    __shared__ __align__(16) u16 Al[2][BM * 64];
    __shared__ __align__(16) u16 Bl[2][BM * 64];

    const int tid = threadIdx.x, w = tid >> 6, lane = tid & 63;
    const int wm = w >> 2, wn = w & 3;            // 2x4 wave grid; per-wave 128x64 out
    const int srow = lane >> 3;                   // 0..7
    const int dslot = (lane & 7) ^ srow;          // pre-swizzled source 16B slot
    const int fr = lane & 15, kg = lane >> 4;

    int raO[8], rbO[4];
    #pragma unroll
    for (int fm = 0; fm < 8; ++fm) raO[fm] = (wm * 128 + fm * 16 + fr) * 64;
    #pragma unroll
    for (int fn = 0; fn < 4; ++fn) rbO[fn] = (wn * 64 + fn * 16 + fr) * 64;
    const int s0 = ((kg)     ^ (lane & 7)) * 8;   // kstep0 swizzled slot offset (elems)
    const int s1 = ((4 + kg) ^ (lane & 7)) * 8;   // kstep1

    // anti-phase skew: odd waves run k-half 1 first, even waves k-half 0 first.
    // Both halves accumulate into the same acc cells (K-sum), so order is free;
    // at any instant ~half the waves are in ds_read while half are in MFMA.
    const int wodd = w & 1;

    f32x4 acc4[8][4];
    #pragma unroll
    for (int i = 0; i < 8; ++i)
        #pragma unroll
        for (int j = 0; j < 4; ++j)
            acc4[i][j] = {0.f, 0.f, 0.f, 0.f};

    // staging: wave w covers rows w*32 + q*8 + srow (q=0..3), 8 waves -> 256 rows
    const size_t aRow = (size_t)(bm  + w * 32 + srow) * DIM + dslot * 8;
    const size_t bRow = (size_t)(bnc + w * 32 + srow) * DIM + dslot * 8;

#define STAGE(kt, buf)                                                              \
    {                                                                               \
        _Pragma("unroll")                                                           \
        for (int q = 0; q < 4; ++q) {                                               \
            const int rb_ = w * 32 + q * 8;                                         \
            gload16(A + aRow + (size_t)q * 8 * DIM + (kt) * 64, &Al[buf][rb_ * 64]);\
            gload16(B + bRow + (size_t)q * 8 * DIM + (kt) * 64, &Bl[buf][rb_ * 64]);\
        }                                                                           \
    }

    // prologue: stage tiles 0 and 1; wait tile 0 (tile 1's 8 loads stay in flight)
    STAGE(0, 0)
    STAGE(1, 1)
    asm volatile("s_waitcnt vmcnt(8)" ::: "memory");
    __builtin_amdgcn_s_barrier();

    #pragma unroll
    for (int kt = 0; kt < NT; ++kt) {
        const int cur = kt & 1;
        const u16* Ab = &Al[cur][0];
        const u16* Bb = &Bl[cur][0];

        #pragma unroll
        for (int ph = 0; ph < 2; ++ph) {
            const int so = (ph ^ wodd) ? s1 : s0;   // wave-parity phase order
            bf16x8 af[8], bfr[4];
            #pragma unroll
            for (int fm = 0; fm < 8; ++fm) af[fm] = *(const bf16x8*)(Ab + raO[fm] + so);
            #pragma unroll
            for (int fn = 0; fn < 4; ++fn) bfr[fn] = *(const bf16x8*)(Bb + rbO[fn] + so);
            __builtin_amdgcn_s_setprio(1);
            #pragma unroll
            for (int fm = 0; fm < 8; ++fm)
                #pragma unroll
                for (int fn = 0; fn < 4; ++fn)
                    acc4[fm][fn] = __builtin_amdgcn_mfma_f32_16x16x32_bf16(af[fm], bfr[fn], acc4[fm][fn], 0, 0, 0);
            __builtin_amdgcn_s_setprio(0);
        }

        if (kt + 1 < NT) {
            asm volatile("s_waitcnt lgkmcnt(0)" ::: "memory");
            __builtin_amdgcn_s_barrier();              // buf[cur] reads retired block-wide
            if (kt + 2 < NT) {
                STAGE(kt + 2, cur)                     // refill just-freed buffer
                asm volatile("s_waitcnt vmcnt(8)" ::: "memory");  // tile kt+1 landed
            } else {
                asm volatile("s_waitcnt vmcnt(0)" ::: "memory");  // last tile: drain
            }
            __builtin_amdgcn_s_barrier();
        }
    }
#undef STAGE

    // ---- epilogue: d = an + bn - 2*dot ; 3-bandwidth gaussian sum via t = exp(-d/12) ----
    float lsum = 0.f;
    #pragma unroll
    for (int fm = 0; fm < 8; ++fm) {
        const f32x4 anv = *(const f32x4*)(an + bm + wm * 128 + fm * 16 + kg * 4);
        #pragma unroll
        for (int fn = 0; fn < 4; ++fn) {
            const float bnv = bn[bnc + wn * 64 + fn * 16 + fr];
            #pragma unroll
            for (int j = 0; j < 4; ++j) {
                float d  = anv[j] + bnv - 2.0f * acc4[fm][fn][j];
                float t  = __expf(d * (-1.0f / 12.0f));
                float t2 = t * t, t3 = t2 * t;
                lsum += t2 + t3 + t3 * t3;   // bw3 + bw2 + bw1
            }
        }
    }
    #pragma unroll
    for (int off = 32; off; off >>= 1) lsum += __shfl_down(lsum, off, 64);

    // wsum aliased onto buf0 A-tile (kt=7 read buf1 only; __syncthreads orders the write)
    float* wsum = (float*)&Al[0][0];
    if (lane == 0) wsum[w] = lsum;
    __syncthreads();
    if (tid == 0) {
        float bs = 0.f;
        #pragma unroll
        for (int i = 0; i < 8; ++i) bs += wsum[i];
        atomicAdd(acc, (double)(bs * wgt));
    }
}

// ================= launch =================
extern "C" void kernel_launch(void* const* d_in, const int* in_sizes, int n_in,
                              void* d_out, int out_size, void* d_ws, size_t ws_size,
                              hipStream_t stream) {
    const float* x = (const float*)d_in[0];
    const float* y = (const float*)d_in[1];
    float* out = (float*)d_out;
    char* ws = (char*)d_ws;

    const size_t bBytes = (size_t)NR * DIM * 2;      // 8 MiB each
    u16*   xb = (u16*)ws;
    u16*   yb = (u16*)(ws + bBytes);
    float* xn = (float*)(ws + 2 * bBytes);
    float* yn = (float*)(ws + 2 * bBytes + (size_t)NR * 4);
    double* acc = (double*)(ws + 2 * bBytes + 2 * (size_t)NR * 4);

    zero_kernel<<<1, 64, 0, stream>>>(acc);
    conv_bf16<<<(2 * NR) / 4, 256, 0, stream>>>(x, y, xb, yb, xn, yn);
    mmd_bf16<<<2080, 512, 0, stream>>>(xb, yb, xn, yn, acc);
    finalize_kernel<<<1, 64, 0, stream>>>(acc, out);
}